// Round 6
// baseline (393.884 us; speedup 1.0000x reference)
//
#include <hip/hip_runtime.h>
#include <hip/hip_bf16.h>
#include <cstdint>
#include <cstddef>

typedef _Float16 f16;
typedef _Float16 f16x8 __attribute__((ext_vector_type(8)));
typedef _Float16 f16x4 __attribute__((ext_vector_type(4)));
typedef float    f32x4 __attribute__((ext_vector_type(4)));

#define DM 1024   // d_model
#define NBE 256   // entities per batch row

// ================= prep: gather + conv(WK,WO) + tr(WQ) + wobk + bqbk =================
__global__ __launch_bounds__(256) void prep(
    const float* __restrict__ ent_emb, const int* __restrict__ idx,
    f16* __restrict__ Egh,
    const float* __restrict__ WK_w, f16* __restrict__ WKr,
    const float* __restrict__ WO_w, f16* __restrict__ WOr,
    const float* __restrict__ WQ_w, f16* __restrict__ WQt,
    const float* __restrict__ WQ_b, const float* __restrict__ WK_b,
    float* __restrict__ wobk, float* __restrict__ bqbk) {
  __shared__ float ts[64][65];
  __shared__ float sm4[4];
  int blk = blockIdx.x, tid = threadIdx.x;
  if (blk < 4096) {                      // gather entities -> f16 (zero masked)
    int e = idx[blk];
    int c = tid * 4;
    f16x4 o;
    if (e < 0) {
      o.x = (f16)0.f; o.y = (f16)0.f; o.z = (f16)0.f; o.w = (f16)0.f;
    } else {
      float4 v = *(const float4*)(ent_emb + (size_t)e * DM + c);
      o.x = (f16)v.x; o.y = (f16)v.y; o.z = (f16)v.z; o.w = (f16)v.w;
    }
    *(f16x4*)(Egh + (size_t)blk * DM + c) = o;
  } else if (blk < 4608) {               // WK f32 -> f16 (row-major)
    int i = (blk - 4096) * 2048 + tid * 8;
    float4 a = *(const float4*)(WK_w + i);
    float4 b = *(const float4*)(WK_w + i + 4);
    f16x8 o;
    o[0] = (f16)a.x; o[1] = (f16)a.y; o[2] = (f16)a.z; o[3] = (f16)a.w;
    o[4] = (f16)b.x; o[5] = (f16)b.y; o[6] = (f16)b.z; o[7] = (f16)b.w;
    *(f16x8*)(WKr + i) = o;
  } else if (blk < 5120) {               // WO f32 -> f16 (row-major)
    int i = (blk - 4608) * 2048 + tid * 8;
    float4 a = *(const float4*)(WO_w + i);
    float4 b = *(const float4*)(WO_w + i + 4);
    f16x8 o;
    o[0] = (f16)a.x; o[1] = (f16)a.y; o[2] = (f16)a.z; o[3] = (f16)a.w;
    o[4] = (f16)b.x; o[5] = (f16)b.y; o[6] = (f16)b.z; o[7] = (f16)b.w;
    *(f16x8*)(WOr + i) = o;
  } else if (blk < 5376) {               // transpose WQ -> f16
    int t = blk - 5120;
    int bi = ((t >> 4) & 15) * 64, bj = (t & 15) * 64;
    int tx = tid & 63, ty = tid >> 6;
#pragma unroll
    for (int k = 0; k < 16; ++k) {
      int r = ty * 16 + k;
      ts[r][tx] = WQ_w[(size_t)(bi + r) * DM + bj + tx];
    }
    __syncthreads();
#pragma unroll
    for (int k = 0; k < 16; ++k) {
      int r = ty * 16 + k;
      WQt[(size_t)(bj + r) * DM + bi + tx] = (f16)ts[tx][r];
    }
  } else if (blk < 5632) {               // wobk[r] = WO[r,:].bk
    int w = tid >> 6, lane = tid & 63;
    int r = (blk - 5376) * 4 + w;
    const float* a = WO_w + (size_t)r * 1024;
    float s = 0.f;
#pragma unroll
    for (int i = 0; i < 16; ++i) s += a[lane + i * 64] * WK_b[lane + i * 64];
#pragma unroll
    for (int d = 1; d < 64; d <<= 1) s += __shfl_xor(s, d);
    if (lane == 0) wobk[r] = s;
  } else {                               // bqbk = bq.bk
    float s = 0.f;
    for (int i = tid; i < 1024; i += 256) s += WK_b[i] * WQ_b[i];
#pragma unroll
    for (int d = 1; d < 64; d <<= 1) s += __shfl_xor(s, d);
    int w = tid >> 6;
    if ((tid & 63) == 0) sm4[w] = s;
    __syncthreads();
    if (tid == 0) bqbk[0] = sm4[0] + sm4[1] + sm4[2] + sm4[3];
  }
}

// ================= generic TN GEMM core: C[M,N] = A[M,K] @ B[N,K]^T =================
// EPI 0: f16 out, plain.  EPI 3: f16 out, + rowbias[r], zero col if colidx[cN]<0
template <int EPI>
__device__ __forceinline__ void gemm_core(
    const f16* __restrict__ A, const f16* __restrict__ B,
    const float* __restrict__ rowbias, const int* __restrict__ colidx,
    f16* __restrict__ C, int N, int K, int m0, int n0,
    f16* __restrict__ smA, f16* __restrict__ smB) {
  int tid = threadIdx.x;
  int lane = tid & 63, w = tid >> 6;
  int wr = w >> 1, wc = w & 1;
  int l15 = lane & 15, lhi = lane >> 4;
  const f16* Ab = A + (size_t)m0 * K;
  const f16* Bb = B + (size_t)n0 * K;

  f32x4 acc[4][4];
  f32x4 z4 = {0.f, 0.f, 0.f, 0.f};
#pragma unroll
  for (int i = 0; i < 4; ++i)
#pragma unroll
    for (int j = 0; j < 4; ++j) acc[i][j] = z4;

  f16x8 ra[4], rb[4];
#pragma unroll
  for (int p = 0; p < 4; ++p) {
    int e = p * 2048 + tid * 8;
    int row = e >> 6, c8 = (e & 63) >> 3;
    ra[p] = *(const f16x8*)(Ab + (size_t)row * K + c8 * 8);
    rb[p] = *(const f16x8*)(Bb + (size_t)row * K + c8 * 8);
  }
#pragma unroll
  for (int p = 0; p < 4; ++p) {
    int e = p * 2048 + tid * 8;
    int row = e >> 6, c8 = (e & 63) >> 3;
    int off = row * 64 + ((c8 ^ (row & 7)) << 3);
    *(f16x8*)(&smA[off]) = ra[p];
    *(f16x8*)(&smB[off]) = rb[p];
  }

  int nk = K >> 6;
  for (int kt = 0; kt < nk; ++kt) {
    int cur = kt & 1;
    bool pre = (kt + 1 < nk);
    __syncthreads();
    if (pre) {
      const f16* An = Ab + (kt + 1) * 64;
      const f16* Bn = Bb + (kt + 1) * 64;
#pragma unroll
      for (int p = 0; p < 4; ++p) {
        int e = p * 2048 + tid * 8;
        int row = e >> 6, c8 = (e & 63) >> 3;
        ra[p] = *(const f16x8*)(An + (size_t)row * K + c8 * 8);
        rb[p] = *(const f16x8*)(Bn + (size_t)row * K + c8 * 8);
      }
    }
    const f16* As = smA + cur * 8192;
    const f16* Bs = smB + cur * 8192;
    __builtin_amdgcn_s_setprio(1);
#pragma unroll
    for (int kk = 0; kk < 2; ++kk) {
      int c8 = kk * 4 + lhi;
      f16x8 af[4], bf[4];
#pragma unroll
      for (int mi = 0; mi < 4; ++mi) {
        int r = wr * 64 + mi * 16 + l15;
        af[mi] = *(const f16x8*)(As + r * 64 + ((c8 ^ (r & 7)) << 3));
      }
#pragma unroll
      for (int ni = 0; ni < 4; ++ni) {
        int r = wc * 64 + ni * 16 + l15;
        bf[ni] = *(const f16x8*)(Bs + r * 64 + ((c8 ^ (r & 7)) << 3));
      }
#pragma unroll
      for (int mi = 0; mi < 4; ++mi)
#pragma unroll
        for (int ni = 0; ni < 4; ++ni)
          acc[mi][ni] = __builtin_amdgcn_mfma_f32_16x16x32_f16(af[mi], bf[ni], acc[mi][ni], 0, 0, 0);
    }
    __builtin_amdgcn_s_setprio(0);
    if (pre) {
#pragma unroll
      for (int p = 0; p < 4; ++p) {
        int e = p * 2048 + tid * 8;
        int row = e >> 6, c8 = (e & 63) >> 3;
        int off = (cur ^ 1) * 8192 + row * 64 + ((c8 ^ (row & 7)) << 3);
        *(f16x8*)(&smA[off]) = ra[p];
        *(f16x8*)(&smB[off]) = rb[p];
      }
    }
  }

#pragma unroll
  for (int mi = 0; mi < 4; ++mi) {
#pragma unroll
    for (int j = 0; j < 4; ++j) {
      int r = m0 + wr * 64 + mi * 16 + lhi * 4 + j;
      float rbv = (EPI == 3) ? rowbias[r] : 0.f;
#pragma unroll
      for (int ni = 0; ni < 4; ++ni) {
        int cN = n0 + wc * 64 + ni * 16 + l15;
        float v = acc[mi][ni][j];
        if (EPI == 3) { v += rbv; if (colidx[cN] < 0) v = 0.f; }
        C[(size_t)r * N + cN] = (f16)v;
      }
    }
  }
}

// E0 = Eg @ WK^T   (M=4096, N=1024, K=1024)
__global__ __launch_bounds__(256) void gemm_e0(const f16* __restrict__ Egh,
                                               const f16* __restrict__ WKr,
                                               f16* __restrict__ E0) {
  __shared__ __align__(16) f16 sA[2 * 8192], sB[2 * 8192];
  gemm_core<0>(Egh, WKr, nullptr, nullptr, E0, 1024, 1024,
               blockIdx.y * 128, blockIdx.x * 128, sA, sB);
}

// Tp = E0 @ WQ (256 blks); EWot = WO @ E0^T + wobk, masked (256 blks); cvec (1024 blks)
__global__ __launch_bounds__(256) void stage3(
    const f16* __restrict__ E0, const f16* __restrict__ WQt,
    const f16* __restrict__ WOr, const float* __restrict__ wobk,
    const int* __restrict__ idx, const float* __restrict__ bq,
    const float* __restrict__ bqbk,
    f16* __restrict__ Tp, f16* __restrict__ EWot, float* __restrict__ cvec) {
  __shared__ __align__(16) f16 sA[2 * 8192], sB[2 * 8192];
  int blk = blockIdx.x;
  if (blk < 256) {
    gemm_core<0>(E0, WQt, nullptr, nullptr, Tp, 1024, 1024,
                 (blk >> 3) * 128, (blk & 7) * 128, sA, sB);
  } else if (blk < 512) {
    int t = blk - 256;
    gemm_core<3>(WOr, E0, wobk, idx, EWot, 4096, 1024,
                 (t >> 5) * 128, (t & 31) * 128, sA, sB);
  } else {
    int t = blk - 512;
    int w = threadIdx.x >> 6, lane = threadIdx.x & 63;
    int n = t * 4 + w;
    const f16* e = E0 + (size_t)n * 1024;
    float s = 0.f;
#pragma unroll
    for (int i = 0; i < 16; ++i) { int k = lane + i * 64; s += (float)e[k] * bq[k]; }
#pragma unroll
    for (int d = 1; d < 64; d <<= 1) s += __shfl_xor(s, d);
    if (lane == 0)
      cvec[n] = s + bqbk[0] + ((idx[n] < 0) ? -100000.0f : 0.0f);
  }
}

// ================= fused attention v5: barrier-free K-loops, direct L2 fragment loads ==
// grid 512 x 512 threads: b = id&15 (XCD affinity), lt = id>>4 (32 tiles x 32 rows).
// 8 waves: wm = w>>2 (16-row half), we = w&3 (64-entity / 256-d quarter).
// phase1: S = q(f32->f16) @ Tp^T, K=1024, frags straight from global (L2).
// phase2: 3-barrier cross-wave softmax (cvec has mask; 1/32 in normalizer).
// phase3: O = P(smP) @ EWot^T, K=256, frags straight from global (L2).
__global__ __launch_bounds__(512, 4) void attn5(
    const float* __restrict__ query, const f16* __restrict__ Tp,
    const f16* __restrict__ EWot, const float* __restrict__ cvec,
    f16* __restrict__ O16) {
  __shared__ __align__(16) f16 smP[32 * 256];      // 16 KB
  __shared__ float smMax[4][32], smSum[4][32];
  int id = blockIdx.x;
  int b = id & 15, lt = id >> 4;
  int tid = threadIdx.x, lane = tid & 63, w = tid >> 6;
  int l15 = lane & 15, lhi = lane >> 4;
  int wm = w >> 2, we = w & 3;
  const float* Qb = query + (size_t)(b * 1024 + lt * 32 + wm * 16) * DM;
  const f16* Tb = Tp + (size_t)(b * NBE + we * 64) * DM;

  f32x4 z4 = {0.f, 0.f, 0.f, 0.f};
  f32x4 acc[4];
#pragma unroll
  for (int i = 0; i < 4; ++i) acc[i] = z4;

  // ---- phase 1: no barriers, direct loads ----
  const float* qrow = Qb + (size_t)l15 * DM + lhi * 8;
  for (int kt = 0; kt < 16; ++kt) {
    int k0 = kt * 64;
    f16x8 bb[4][2];
#pragma unroll
    for (int ni = 0; ni < 4; ++ni)
#pragma unroll
      for (int kk = 0; kk < 2; ++kk)
        bb[ni][kk] = *(const f16x8*)(Tb + (size_t)(ni * 16 + l15) * DM + k0 + kk * 32 + lhi * 8);
    f16x8 aq[2];
#pragma unroll
    for (int kk = 0; kk < 2; ++kk) {
      float4 qa = *(const float4*)(qrow + k0 + kk * 32);
      float4 qc = *(const float4*)(qrow + k0 + kk * 32 + 4);
      f16x8 h;
      h[0] = (f16)qa.x; h[1] = (f16)qa.y; h[2] = (f16)qa.z; h[3] = (f16)qa.w;
      h[4] = (f16)qc.x; h[5] = (f16)qc.y; h[6] = (f16)qc.z; h[7] = (f16)qc.w;
      aq[kk] = h;
    }
#pragma unroll
    for (int kk = 0; kk < 2; ++kk)
#pragma unroll
      for (int ni = 0; ni < 4; ++ni)
        acc[ni] = __builtin_amdgcn_mfma_f32_16x16x32_f16(aq[kk], bb[ni][kk], acc[ni], 0, 0, 0);
  }

  // ---- phase 2: softmax (cross-we combine) ----
  float cv[4];
#pragma unroll
  for (int ni = 0; ni < 4; ++ni)
    cv[ni] = cvec[b * NBE + we * 64 + ni * 16 + l15];
  int rbase = wm * 16 + lhi * 4;
#pragma unroll
  for (int j = 0; j < 4; ++j) {
    float m = -3.0e38f;
#pragma unroll
    for (int ni = 0; ni < 4; ++ni) m = fmaxf(m, acc[ni][j] + cv[ni]);
    m = fmaxf(m, __shfl_xor(m, 1));
    m = fmaxf(m, __shfl_xor(m, 2));
    m = fmaxf(m, __shfl_xor(m, 4));
    m = fmaxf(m, __shfl_xor(m, 8));
    if (l15 == 0) smMax[we][rbase + j] = m;
  }
  __syncthreads();
#pragma unroll
  for (int j = 0; j < 4; ++j) {
    int r = rbase + j;
    float fm = fmaxf(fmaxf(smMax[0][r], smMax[1][r]), fmaxf(smMax[2][r], smMax[3][r]));
    float s = 0.f;
#pragma unroll
    for (int ni = 0; ni < 4; ++ni) {
      float e = __expf(acc[ni][j] + cv[ni] - fm);
      acc[ni][j] = e;
      s += e;
    }
    s += __shfl_xor(s, 1);
    s += __shfl_xor(s, 2);
    s += __shfl_xor(s, 4);
    s += __shfl_xor(s, 8);
    if (l15 == 0) smSum[we][r] = s;
  }
  __syncthreads();
#pragma unroll
  for (int j = 0; j < 4; ++j) {
    int r = rbase + j;
    float inv = 0.03125f / (smSum[0][r] + smSum[1][r] + smSum[2][r] + smSum[3][r]);
#pragma unroll
    for (int ni = 0; ni < 4; ++ni) {
      int col = we * 64 + ni * 16 + l15;
      smP[r * 256 + (((col >> 3) ^ (r & 7)) << 3) + (col & 7)] = (f16)(acc[ni][j] * inv);
    }
  }
  __syncthreads();

  // ---- phase 3: O = P @ EWot^T, direct B loads ----
  // A-frags (reused across all dc/ni): row wm*16+l15, k-cols ks*32+lhi*8
  f16x8 pa[8];
  {
    int pr = wm * 16 + l15;
#pragma unroll
    for (int ks = 0; ks < 8; ++ks)
      pa[ks] = *(const f16x8*)(smP + pr * 256 + (((ks * 4 + lhi) ^ (pr & 7)) << 3));
  }
  const f16* Eb = EWot + b * NBE + lhi * 8;        // row stride 4096
  f16* Ob = O16 + (size_t)(b * 1024 + lt * 32 + wm * 16) * DM;
  for (int dc = 0; dc < 4; ++dc) {
    f32x4 accv[4];
#pragma unroll
    for (int i = 0; i < 4; ++i) accv[i] = z4;
#pragma unroll
    for (int ks = 0; ks < 8; ++ks) {
      f16x8 bv[4];
#pragma unroll
      for (int ni = 0; ni < 4; ++ni)
        bv[ni] = *(const f16x8*)(Eb + (size_t)(we * 256 + dc * 64 + ni * 16 + l15) * 4096 + ks * 32);
#pragma unroll
      for (int ni = 0; ni < 4; ++ni)
        accv[ni] = __builtin_amdgcn_mfma_f32_16x16x32_f16(pa[ks], bv[ni], accv[ni], 0, 0, 0);
    }
#pragma unroll
    for (int ni = 0; ni < 4; ++ni)
#pragma unroll
      for (int j = 0; j < 4; ++j)
        Ob[(size_t)(lhi * 4 + j) * DM + we * 256 + dc * 64 + ni * 16 + l15] = (f16)accv[ni][j];
  }
}

// ================= LayerNorm: out = LN(O16 + bo) * g + b (1 wave / row) =================
__global__ __launch_bounds__(256) void ln5(const f16* __restrict__ X,
                                           const float* __restrict__ bo,
                                           const float* __restrict__ g,
                                           const float* __restrict__ bta,
                                           float* __restrict__ out) {
  int lane = threadIdx.x & 63;
  size_t row = blockIdx.x * 4 + (threadIdx.x >> 6);
  const f16* x = X + row * DM + lane * 16;
  f16x8 h0 = *(const f16x8*)(x);
  f16x8 h1 = *(const f16x8*)(x + 8);
  float v[16];
#pragma unroll
  for (int i = 0; i < 8; ++i) { v[i] = (float)h0[i]; v[8 + i] = (float)h1[i]; }
#pragma unroll
  for (int i = 0; i < 16; ++i) v[i] += bo[lane * 16 + i];
  float s = 0.f, q = 0.f;
#pragma unroll
  for (int i = 0; i < 16; ++i) { s += v[i]; q += v[i] * v[i]; }
#pragma unroll
  for (int d = 1; d < 64; d <<= 1) { s += __shfl_xor(s, d); q += __shfl_xor(q, d); }
  float mu = s * (1.0f / DM);
  float var = q * (1.0f / DM) - mu * mu;
  float rs = rsqrtf(var + 1e-5f);
  float* o = out + row * DM + lane * 16;
#pragma unroll
  for (int i = 0; i < 16; ++i)
    o[i] = (v[i] - mu) * rs * g[lane * 16 + i] + bta[lane * 16 + i];
}

extern "C" void kernel_launch(void* const* d_in, const int* in_sizes, int n_in,
                              void* d_out, int out_size, void* d_ws, size_t ws_size,
                              hipStream_t stream) {
  const float* query   = (const float*)d_in[0];
  const float* ent_emb = (const float*)d_in[1];
  const int*   idx     = (const int*)d_in[2];
  const float* WQ_w = (const float*)d_in[4];
  const float* WQ_b = (const float*)d_in[5];
  const float* WK_w = (const float*)d_in[6];
  const float* WK_b = (const float*)d_in[7];
  const float* WO_w = (const float*)d_in[8];
  const float* WO_b = (const float*)d_in[9];
  const float* ln_g = (const float*)d_in[10];
  const float* ln_b = (const float*)d_in[11];
  float* out = (float*)d_out;

  char* p = (char*)d_ws;
  f16* Egh  = (f16*)p;  p += (size_t)4096 * 1024 * 2;        // 8MB
  f16* WKr  = (f16*)p;  p += (size_t)1024 * 1024 * 2;
  f16* WOr  = (f16*)p;  p += (size_t)1024 * 1024 * 2;
  f16* WQt  = (f16*)p;  p += (size_t)1024 * 1024 * 2;
  f16* E0   = (f16*)p;  p += (size_t)4096 * 1024 * 2;        // 8MB
  f16* Tp   = (f16*)p;  p += (size_t)4096 * 1024 * 2;        // 8MB
  f16* EWot = (f16*)p;  p += (size_t)1024 * 4096 * 2;        // 8MB
  f16* O16  = (f16*)p;  p += (size_t)16384 * 1024 * 2;       // 32MB
  float* wobk = (float*)p; p += 1024 * 4;
  float* bqbk = (float*)p; p += 4;
  float* cvec = (float*)p; p += 4096 * 4;

  // prep: gather, conv WK/WO, tr WQ, wobk, bqbk
  prep<<<5633, 256, 0, stream>>>(ent_emb, idx, Egh, WK_w, WKr, WO_w, WOr,
                                 WQ_w, WQt, WQ_b, WK_b, wobk, bqbk);
  // E0 = Eg @ WK^T
  gemm_e0<<<dim3(8, 32), 256, 0, stream>>>(Egh, WKr, E0);
  // Tp = E0 @ WQ ; EWot = WO @ E0^T + wobk (masked) ; cvec = E0.bq + bqbk + mask
  stage3<<<1536, 256, 0, stream>>>(E0, WQt, WOr, wobk, idx, WQ_b, bqbk,
                                   Tp, EWot, cvec);
  // fused attention -> O16 (f16, pre-bias, pre-scaled)
  attn5<<<512, 512, 0, stream>>>(query, Tp, EWot, cvec, O16);
  // out = LN(O16 + bo)
  ln5<<<4096, 256, 0, stream>>>(O16, WO_b, ln_g, ln_b, out);
}

// Round 7
// 297.184 us; speedup vs baseline: 1.3254x; 1.3254x over previous
//
#include <hip/hip_runtime.h>
#include <hip/hip_bf16.h>
#include <cstdint>
#include <cstddef>

typedef _Float16 f16;
typedef _Float16 f16x8 __attribute__((ext_vector_type(8)));
typedef _Float16 f16x4 __attribute__((ext_vector_type(4)));
typedef float    f32x4 __attribute__((ext_vector_type(4)));

#define DM 1024   // d_model
#define NBE 256   // entities per batch row

// ================= prep: gather + conv(WK,WO) + tr(WQ) + wobk + bqbk =================
__global__ __launch_bounds__(256) void prep(
    const float* __restrict__ ent_emb, const int* __restrict__ idx,
    f16* __restrict__ Egh,
    const float* __restrict__ WK_w, f16* __restrict__ WKr,
    const float* __restrict__ WO_w, f16* __restrict__ WOr,
    const float* __restrict__ WQ_w, f16* __restrict__ WQt,
    const float* __restrict__ WQ_b, const float* __restrict__ WK_b,
    float* __restrict__ wobk, float* __restrict__ bqbk) {
  __shared__ float ts[64][65];
  __shared__ float sm4[4];
  int blk = blockIdx.x, tid = threadIdx.x;
  if (blk < 4096) {                      // gather entities -> f16 (zero masked)
    int e = idx[blk];
    int c = tid * 4;
    f16x4 o;
    if (e < 0) {
      o.x = (f16)0.f; o.y = (f16)0.f; o.z = (f16)0.f; o.w = (f16)0.f;
    } else {
      float4 v = *(const float4*)(ent_emb + (size_t)e * DM + c);
      o.x = (f16)v.x; o.y = (f16)v.y; o.z = (f16)v.z; o.w = (f16)v.w;
    }
    *(f16x4*)(Egh + (size_t)blk * DM + c) = o;
  } else if (blk < 4608) {               // WK f32 -> f16 (row-major)
    int i = (blk - 4096) * 2048 + tid * 8;
    float4 a = *(const float4*)(WK_w + i);
    float4 b = *(const float4*)(WK_w + i + 4);
    f16x8 o;
    o[0] = (f16)a.x; o[1] = (f16)a.y; o[2] = (f16)a.z; o[3] = (f16)a.w;
    o[4] = (f16)b.x; o[5] = (f16)b.y; o[6] = (f16)b.z; o[7] = (f16)b.w;
    *(f16x8*)(WKr + i) = o;
  } else if (blk < 5120) {               // WO f32 -> f16 (row-major)
    int i = (blk - 4608) * 2048 + tid * 8;
    float4 a = *(const float4*)(WO_w + i);
    float4 b = *(const float4*)(WO_w + i + 4);
    f16x8 o;
    o[0] = (f16)a.x; o[1] = (f16)a.y; o[2] = (f16)a.z; o[3] = (f16)a.w;
    o[4] = (f16)b.x; o[5] = (f16)b.y; o[6] = (f16)b.z; o[7] = (f16)b.w;
    *(f16x8*)(WOr + i) = o;
  } else if (blk < 5376) {               // transpose WQ -> f16
    int t = blk - 5120;
    int bi = ((t >> 4) & 15) * 64, bj = (t & 15) * 64;
    int tx = tid & 63, ty = tid >> 6;
#pragma unroll
    for (int k = 0; k < 16; ++k) {
      int r = ty * 16 + k;
      ts[r][tx] = WQ_w[(size_t)(bi + r) * DM + bj + tx];
    }
    __syncthreads();
#pragma unroll
    for (int k = 0; k < 16; ++k) {
      int r = ty * 16 + k;
      WQt[(size_t)(bj + r) * DM + bi + tx] = (f16)ts[tx][r];
    }
  } else if (blk < 5632) {               // wobk[r] = WO[r,:].bk
    int w = tid >> 6, lane = tid & 63;
    int r = (blk - 5376) * 4 + w;
    const float* a = WO_w + (size_t)r * 1024;
    float s = 0.f;
#pragma unroll
    for (int i = 0; i < 16; ++i) s += a[lane + i * 64] * WK_b[lane + i * 64];
#pragma unroll
    for (int d = 1; d < 64; d <<= 1) s += __shfl_xor(s, d);
    if (lane == 0) wobk[r] = s;
  } else {                               // bqbk = bq.bk
    float s = 0.f;
    for (int i = tid; i < 1024; i += 256) s += WK_b[i] * WQ_b[i];
#pragma unroll
    for (int d = 1; d < 64; d <<= 1) s += __shfl_xor(s, d);
    int w = tid >> 6;
    if ((tid & 63) == 0) sm4[w] = s;
    __syncthreads();
    if (tid == 0) bqbk[0] = sm4[0] + sm4[1] + sm4[2] + sm4[3];
  }
}

// ================= generic TN GEMM core: C[M,N] = A[M,K] @ B[N,K]^T =================
// EPI 0: f16 out, plain.  EPI 3: f16 out, + rowbias[r], zero col if colidx[cN]<0
template <int EPI>
__device__ __forceinline__ void gemm_core(
    const f16* __restrict__ A, const f16* __restrict__ B,
    const float* __restrict__ rowbias, const int* __restrict__ colidx,
    f16* __restrict__ C, int N, int K, int m0, int n0,
    f16* __restrict__ smA, f16* __restrict__ smB) {
  int tid = threadIdx.x;
  int lane = tid & 63, w = tid >> 6;
  int wr = w >> 1, wc = w & 1;
  int l15 = lane & 15, lhi = lane >> 4;
  const f16* Ab = A + (size_t)m0 * K;
  const f16* Bb = B + (size_t)n0 * K;

  f32x4 acc[4][4];
  f32x4 z4 = {0.f, 0.f, 0.f, 0.f};
#pragma unroll
  for (int i = 0; i < 4; ++i)
#pragma unroll
    for (int j = 0; j < 4; ++j) acc[i][j] = z4;

  f16x8 ra[4], rb[4];
#pragma unroll
  for (int p = 0; p < 4; ++p) {
    int e = p * 2048 + tid * 8;
    int row = e >> 6, c8 = (e & 63) >> 3;
    ra[p] = *(const f16x8*)(Ab + (size_t)row * K + c8 * 8);
    rb[p] = *(const f16x8*)(Bb + (size_t)row * K + c8 * 8);
  }
#pragma unroll
  for (int p = 0; p < 4; ++p) {
    int e = p * 2048 + tid * 8;
    int row = e >> 6, c8 = (e & 63) >> 3;
    int off = row * 64 + ((c8 ^ (row & 7)) << 3);
    *(f16x8*)(&smA[off]) = ra[p];
    *(f16x8*)(&smB[off]) = rb[p];
  }

  int nk = K >> 6;
  for (int kt = 0; kt < nk; ++kt) {
    int cur = kt & 1;
    bool pre = (kt + 1 < nk);
    __syncthreads();
    if (pre) {
      const f16* An = Ab + (kt + 1) * 64;
      const f16* Bn = Bb + (kt + 1) * 64;
#pragma unroll
      for (int p = 0; p < 4; ++p) {
        int e = p * 2048 + tid * 8;
        int row = e >> 6, c8 = (e & 63) >> 3;
        ra[p] = *(const f16x8*)(An + (size_t)row * K + c8 * 8);
        rb[p] = *(const f16x8*)(Bn + (size_t)row * K + c8 * 8);
      }
    }
    const f16* As = smA + cur * 8192;
    const f16* Bs = smB + cur * 8192;
    __builtin_amdgcn_s_setprio(1);
#pragma unroll
    for (int kk = 0; kk < 2; ++kk) {
      int c8 = kk * 4 + lhi;
      f16x8 af[4], bf[4];
#pragma unroll
      for (int mi = 0; mi < 4; ++mi) {
        int r = wr * 64 + mi * 16 + l15;
        af[mi] = *(const f16x8*)(As + r * 64 + ((c8 ^ (r & 7)) << 3));
      }
#pragma unroll
      for (int ni = 0; ni < 4; ++ni) {
        int r = wc * 64 + ni * 16 + l15;
        bf[ni] = *(const f16x8*)(Bs + r * 64 + ((c8 ^ (r & 7)) << 3));
      }
#pragma unroll
      for (int mi = 0; mi < 4; ++mi)
#pragma unroll
        for (int ni = 0; ni < 4; ++ni)
          acc[mi][ni] = __builtin_amdgcn_mfma_f32_16x16x32_f16(af[mi], bf[ni], acc[mi][ni], 0, 0, 0);
    }
    __builtin_amdgcn_s_setprio(0);
    if (pre) {
#pragma unroll
      for (int p = 0; p < 4; ++p) {
        int e = p * 2048 + tid * 8;
        int row = e >> 6, c8 = (e & 63) >> 3;
        int off = (cur ^ 1) * 8192 + row * 64 + ((c8 ^ (row & 7)) << 3);
        *(f16x8*)(&smA[off]) = ra[p];
        *(f16x8*)(&smB[off]) = rb[p];
      }
    }
  }

#pragma unroll
  for (int mi = 0; mi < 4; ++mi) {
#pragma unroll
    for (int j = 0; j < 4; ++j) {
      int r = m0 + wr * 64 + mi * 16 + lhi * 4 + j;
      float rbv = (EPI == 3) ? rowbias[r] : 0.f;
#pragma unroll
      for (int ni = 0; ni < 4; ++ni) {
        int cN = n0 + wc * 64 + ni * 16 + l15;
        float v = acc[mi][ni][j];
        if (EPI == 3) { v += rbv; if (colidx[cN] < 0) v = 0.f; }
        C[(size_t)r * N + cN] = (f16)v;
      }
    }
  }
}

// E0 = Eg @ WK^T   (M=4096, N=1024, K=1024)
__global__ __launch_bounds__(256) void gemm_e0(const f16* __restrict__ Egh,
                                               const f16* __restrict__ WKr,
                                               f16* __restrict__ E0) {
  __shared__ __align__(16) f16 sA[2 * 8192], sB[2 * 8192];
  gemm_core<0>(Egh, WKr, nullptr, nullptr, E0, 1024, 1024,
               blockIdx.y * 128, blockIdx.x * 128, sA, sB);
}

// Tp = E0 @ WQ (256 blks); EWot = WO @ E0^T + wobk, masked (256 blks); cvec (1024 blks)
__global__ __launch_bounds__(256) void stage3(
    const f16* __restrict__ E0, const f16* __restrict__ WQt,
    const f16* __restrict__ WOr, const float* __restrict__ wobk,
    const int* __restrict__ idx, const float* __restrict__ bq,
    const float* __restrict__ bqbk,
    f16* __restrict__ Tp, f16* __restrict__ EWot, float* __restrict__ cvec) {
  __shared__ __align__(16) f16 sA[2 * 8192], sB[2 * 8192];
  int blk = blockIdx.x;
  if (blk < 256) {
    gemm_core<0>(E0, WQt, nullptr, nullptr, Tp, 1024, 1024,
                 (blk >> 3) * 128, (blk & 7) * 128, sA, sB);
  } else if (blk < 512) {
    int t = blk - 256;
    gemm_core<3>(WOr, E0, wobk, idx, EWot, 4096, 1024,
                 (t >> 5) * 128, (t & 31) * 128, sA, sB);
  } else {
    int t = blk - 512;
    int w = threadIdx.x >> 6, lane = threadIdx.x & 63;
    int n = t * 4 + w;
    const f16* e = E0 + (size_t)n * 1024;
    float s = 0.f;
#pragma unroll
    for (int i = 0; i < 16; ++i) { int k = lane + i * 64; s += (float)e[k] * bq[k]; }
#pragma unroll
    for (int d = 1; d < 64; d <<= 1) s += __shfl_xor(s, d);
    if (lane == 0)
      cvec[n] = s + bqbk[0] + ((idx[n] < 0) ? -100000.0f : 0.0f);
  }
}

// ================= fused attention v6: attn3 math + depth-2 register prefetch =========
// grid 512: b = id&15 (XCD affinity), lt = id>>4 (32 tiles of 32 Q-rows).
// 4 waves 2x2: wq = row half (16 rows), wc = entity half (128 cols).
#define P1_LOAD(KT, RQa, RQb, RB) do {                                          \
  RQa = *(const float4*)(Qb + (size_t)qrow * DM + (KT) * 64 + qc0);             \
  RQb = *(const float4*)(Qb + (size_t)qrow * DM + (KT) * 64 + qc0 + 4);         \
  _Pragma("unroll")                                                             \
  for (int p = 0; p < 8; ++p) {                                                 \
    int e = p * 2048 + tid * 8;                                                 \
    int row = e >> 6, c8 = (e & 63) >> 3;                                       \
    RB[p] = *(const f16x8*)(Tb + (size_t)row * DM + (KT) * 64 + c8 * 8);        \
  }                                                                             \
} while (0)

#define P1_STEP(KT, RQa, RQb, RB) do {                                          \
  __syncthreads();                                                              \
  {                                                                             \
    f16x8 h;                                                                    \
    h[0] = (f16)RQa.x; h[1] = (f16)RQa.y; h[2] = (f16)RQa.z; h[3] = (f16)RQa.w; \
    h[4] = (f16)RQb.x; h[5] = (f16)RQb.y; h[6] = (f16)RQb.z; h[7] = (f16)RQb.w; \
    *(f16x8*)(smQ + qrow * 64 + (((qc0 >> 3) ^ (qrow & 7)) << 3)) = h;          \
  }                                                                             \
  _Pragma("unroll")                                                             \
  for (int p = 0; p < 8; ++p) {                                                 \
    int e = p * 2048 + tid * 8;                                                 \
    int row = e >> 6, c8 = (e & 63) >> 3;                                       \
    *(f16x8*)(smB + row * 64 + ((c8 ^ (row & 7)) << 3)) = RB[p];                \
  }                                                                             \
  __syncthreads();                                                              \
  if ((KT) + 2 < 16) P1_LOAD((KT) + 2, RQa, RQb, RB);                           \
  __builtin_amdgcn_s_setprio(1);                                                \
  _Pragma("unroll")                                                             \
  for (int kk = 0; kk < 2; ++kk) {                                              \
    int c8 = kk * 4 + lhi;                                                      \
    int qr = wq * 16 + l15;                                                     \
    f16x8 aq = *(const f16x8*)(smQ + qr * 64 + ((c8 ^ (qr & 7)) << 3));         \
    _Pragma("unroll")                                                           \
    for (int ni = 0; ni < 8; ++ni) {                                            \
      int er = wc * 128 + ni * 16 + l15;                                        \
      f16x8 bb = *(const f16x8*)(smB + er * 64 + ((c8 ^ (er & 7)) << 3));       \
      accs[ni] = __builtin_amdgcn_mfma_f32_16x16x32_f16(aq, bb, accs[ni], 0, 0, 0); \
    }                                                                           \
  }                                                                             \
  __builtin_amdgcn_s_setprio(0);                                                \
} while (0)

#define P3_LOAD(T2, RB) do {                                                    \
  int ndc = (T2) >> 2, nks = (T2) & 3;                                          \
  _Pragma("unroll")                                                             \
  for (int p = 0; p < 8; ++p) {                                                 \
    int e = p * 2048 + tid * 8;                                                 \
    int row = e >> 6, c8 = (e & 63) >> 3;                                       \
    RB[p] = *(const f16x8*)(Eb + (size_t)(ndc * 256 + row) * 4096 + nks * 64 + c8 * 8); \
  }                                                                             \
} while (0)

#define P3_STEP(T, RB) do {                                                     \
  __syncthreads();                                                              \
  _Pragma("unroll")                                                             \
  for (int p = 0; p < 8; ++p) {                                                 \
    int e = p * 2048 + tid * 8;                                                 \
    int row = e >> 6, c8 = (e & 63) >> 3;                                       \
    *(f16x8*)(smB + row * 64 + ((c8 ^ (row & 7)) << 3)) = RB[p];                \
  }                                                                             \
  __syncthreads();                                                              \
  if ((T) + 2 < 16) P3_LOAD((T) + 2, RB);                                       \
  if (((T) & 3) == 0) {                                                         \
    _Pragma("unroll")                                                           \
    for (int i = 0; i < 8; ++i) accv[i] = z4;                                   \
  }                                                                             \
  __builtin_amdgcn_s_setprio(1);                                                \
  _Pragma("unroll")                                                             \
  for (int kk = 0; kk < 2; ++kk) {                                              \
    int pc8 = ((T) & 3) * 8 + kk * 4 + lhi;                                     \
    int qr = wq * 16 + l15;                                                     \
    f16x8 ap = *(const f16x8*)(smP + qr * 256 + ((pc8 ^ (qr & 7)) << 3));       \
    int c8 = kk * 4 + lhi;                                                      \
    _Pragma("unroll")                                                           \
    for (int ni = 0; ni < 8; ++ni) {                                            \
      int er = wc * 128 + ni * 16 + l15;                                        \
      f16x8 bv = *(const f16x8*)(smB + er * 64 + ((c8 ^ (er & 7)) << 3));       \
      accv[ni] = __builtin_amdgcn_mfma_f32_16x16x32_f16(ap, bv, accv[ni], 0, 0, 0); \
    }                                                                           \
  }                                                                             \
  __builtin_amdgcn_s_setprio(0);                                                \
  if (((T) & 3) == 3) {                                                         \
    int dc = (T) >> 2;                                                          \
    _Pragma("unroll")                                                           \
    for (int ni = 0; ni < 8; ++ni)                                              \
      _Pragma("unroll")                                                         \
      for (int j = 0; j < 4; ++j) {                                             \
        int r = wq * 16 + lhi * 4 + j;                                          \
        int col = dc * 256 + wc * 128 + ni * 16 + l15;                          \
        Ob[(size_t)r * DM + col] = (f16)accv[ni][j];                            \
      }                                                                         \
  }                                                                             \
} while (0)

__global__ __launch_bounds__(256, 2) void attn6(
    const float* __restrict__ query, const f16* __restrict__ Tp,
    const f16* __restrict__ EWot, const float* __restrict__ cvec,
    f16* __restrict__ O16) {
  __shared__ __align__(16) char pool[49152];
  f16* smB = (f16*)pool;                 // 256x64 swz
  f16* smP = (f16*)(pool + 32768);       // 32x256 swz
  f16* smQ = (f16*)(pool + 32768);       // 32x64 swz (phase1 alias)
  __shared__ float smMax[64], smSum[64];
  int id = blockIdx.x;
  int b = id & 15, lt = id >> 4;
  int tid = threadIdx.x, lane = tid & 63, w = tid >> 6;
  int l15 = lane & 15, lhi = lane >> 4;
  int wq = w >> 1, wc = w & 1;
  const float* Qb = query + (size_t)(b * 1024 + lt * 32) * DM;
  const f16* Tb = Tp + (size_t)b * NBE * DM;
  const f16* Eb = EWot + (size_t)b * NBE;  // row stride 4096

  f32x4 z4 = {0.f, 0.f, 0.f, 0.f};
  f32x4 accs[8];
#pragma unroll
  for (int i = 0; i < 8; ++i) accs[i] = z4;

  int qrow = tid >> 3, qc0 = (tid & 7) * 8;   // Q stage: 8 f32/thread
  float4 rqAa, rqAb, rqBa, rqBb;
  f16x8 rbA[8], rbB[8];

  // ---- phase 1: depth-2 pipelined ----
  P1_LOAD(0, rqAa, rqAb, rbA);
  P1_LOAD(1, rqBa, rqBb, rbB);
  for (int kt = 0; kt < 16; kt += 2) {
    P1_STEP(kt, rqAa, rqAb, rbA);
    P1_STEP(kt + 1, rqBa, rqBb, rbB);
  }

  // prefetch phase-3 tile 0 — overlaps softmax
  P3_LOAD(0, rbA);

  // ---- phase 2: softmax with cross-wave (wc) combine ----
  float cv[8];
#pragma unroll
  for (int ni = 0; ni < 8; ++ni)
    cv[ni] = cvec[b * NBE + wc * 128 + ni * 16 + l15];
  int rbase = wq * 16 + lhi * 4;
  float mxl[4], sml[4];
#pragma unroll
  for (int j = 0; j < 4; ++j) {
    float m = -3.0e38f;
#pragma unroll
    for (int ni = 0; ni < 8; ++ni) m = fmaxf(m, accs[ni][j] + cv[ni]);
    m = fmaxf(m, __shfl_xor(m, 1));
    m = fmaxf(m, __shfl_xor(m, 2));
    m = fmaxf(m, __shfl_xor(m, 4));
    m = fmaxf(m, __shfl_xor(m, 8));
    mxl[j] = m;
    if (l15 == 0) smMax[wc * 32 + rbase + j] = m;
  }
  __syncthreads();
#pragma unroll
  for (int j = 0; j < 4; ++j) {
    float fm = fmaxf(mxl[j], smMax[(wc ^ 1) * 32 + rbase + j]);
    float s = 0.f;
#pragma unroll
    for (int ni = 0; ni < 8; ++ni) {
      float e = __expf(accs[ni][j] + cv[ni] - fm);
      accs[ni][j] = e;
      s += e;
    }
    s += __shfl_xor(s, 1);
    s += __shfl_xor(s, 2);
    s += __shfl_xor(s, 4);
    s += __shfl_xor(s, 8);
    sml[j] = s;
    if (l15 == 0) smSum[wc * 32 + rbase + j] = s;
  }
  __syncthreads();
#pragma unroll
  for (int j = 0; j < 4; ++j) {
    float inv = 0.03125f / (sml[j] + smSum[(wc ^ 1) * 32 + rbase + j]);
    int r = rbase + j;
#pragma unroll
    for (int ni = 0; ni < 8; ++ni) {
      int col = wc * 128 + ni * 16 + l15;
      int cc8 = col >> 3;
      smP[r * 256 + ((cc8 ^ (r & 7)) << 3) + (col & 7)] = (f16)(accs[ni][j] * inv);
    }
  }

  // prefetch phase-3 tile 1
  P3_LOAD(1, rbB);

  // ---- phase 3: O = P @ EWot^T, depth-2 pipelined ----
  f16* Ob = O16 + (size_t)(b * 1024 + lt * 32) * DM;
  f32x4 accv[8];
  for (int t = 0; t < 16; t += 2) {
    P3_STEP(t, rbA);
    P3_STEP(t + 1, rbB);
  }
}

// ================= LayerNorm: out = LN(O16 + bo) * g + b (1 wave / row) =================
__global__ __launch_bounds__(256) void ln5(const f16* __restrict__ X,
                                           const float* __restrict__ bo,
                                           const float* __restrict__ g,
                                           const float* __restrict__ bta,
                                           float* __restrict__ out) {
  int lane = threadIdx.x & 63;
  size_t row = blockIdx.x * 4 + (threadIdx.x >> 6);
  const f16* x = X + row * DM + lane * 16;
  f16x8 h0 = *(const f16x8*)(x);
  f16x8 h1 = *(const f16x8*)(x + 8);
  float v[16];
#pragma unroll
  for (int i = 0; i < 8; ++i) { v[i] = (float)h0[i]; v[8 + i] = (float)h1[i]; }
#pragma unroll
  for (int i = 0; i < 16; ++i) v[i] += bo[lane * 16 + i];
  float s = 0.f, q = 0.f;
#pragma unroll
  for (int i = 0; i < 16; ++i) { s += v[i]; q += v[i] * v[i]; }
#pragma unroll
  for (int d = 1; d < 64; d <<= 1) { s += __shfl_xor(s, d); q += __shfl_xor(q, d); }
  float mu = s * (1.0f / DM);
  float var = q * (1.0f / DM) - mu * mu;
  float rs = rsqrtf(var + 1e-5f);
  float* o = out + row * DM + lane * 16;
#pragma unroll
  for (int i = 0; i < 16; ++i)
    o[i] = (v[i] - mu) * rs * g[lane * 16 + i] + bta[lane * 16 + i];
}

extern "C" void kernel_launch(void* const* d_in, const int* in_sizes, int n_in,
                              void* d_out, int out_size, void* d_ws, size_t ws_size,
                              hipStream_t stream) {
  const float* query   = (const float*)d_in[0];
  const float* ent_emb = (const float*)d_in[1];
  const int*   idx     = (const int*)d_in[2];
  const float* WQ_w = (const float*)d_in[4];
  const float* WQ_b = (const float*)d_in[5];
  const float* WK_w = (const float*)d_in[6];
  const float* WK_b = (const float*)d_in[7];
  const float* WO_w = (const float*)d_in[8];
  const float* WO_b = (const float*)d_in[9];
  const float* ln_g = (const float*)d_in[10];
  const float* ln_b = (const float*)d_in[11];
  float* out = (float*)d_out;

  char* p = (char*)d_ws;
  f16* Egh  = (f16*)p;  p += (size_t)4096 * 1024 * 2;        // 8MB
  f16* WKr  = (f16*)p;  p += (size_t)1024 * 1024 * 2;
  f16* WOr  = (f16*)p;  p += (size_t)1024 * 1024 * 2;
  f16* WQt  = (f16*)p;  p += (size_t)1024 * 1024 * 2;
  f16* E0   = (f16*)p;  p += (size_t)4096 * 1024 * 2;        // 8MB
  f16* Tp   = (f16*)p;  p += (size_t)4096 * 1024 * 2;        // 8MB
  f16* EWot = (f16*)p;  p += (size_t)1024 * 4096 * 2;        // 8MB
  f16* O16  = (f16*)p;  p += (size_t)16384 * 1024 * 2;       // 32MB
  float* wobk = (float*)p; p += 1024 * 4;
  float* bqbk = (float*)p; p += 4;
  float* cvec = (float*)p; p += 4096 * 4;

  // prep: gather, conv WK/WO, tr WQ, wobk, bqbk
  prep<<<5633, 256, 0, stream>>>(ent_emb, idx, Egh, WK_w, WKr, WO_w, WOr,
                                 WQ_w, WQt, WQ_b, WK_b, wobk, bqbk);
  // E0 = Eg @ WK^T
  gemm_e0<<<dim3(8, 32), 256, 0, stream>>>(Egh, WKr, E0);
  // Tp = E0 @ WQ ; EWot = WO @ E0^T + wobk (masked) ; cvec = E0.bq + bqbk + mask
  stage3<<<1536, 256, 0, stream>>>(E0, WQt, WOr, wobk, idx, WQ_b, bqbk,
                                   Tp, EWot, cvec);
  // fused attention -> O16 (f16, pre-bias, pre-scaled)
  attn6<<<512, 256, 0, stream>>>(query, Tp, EWot, cvec, O16);
  // out = LN(O16 + bo)
  ln5<<<4096, 256, 0, stream>>>(O16, WO_b, ln_g, ln_b, out);
}